// Round 10
// baseline (305.116 us; speedup 1.0000x reference)
//
#include <hip/hip_runtime.h>

typedef __attribute__((ext_vector_type(8))) short short8;
typedef __attribute__((ext_vector_type(4))) short s16x4;
typedef __attribute__((ext_vector_type(4))) float f32x4;

#define AS1 __attribute__((address_space(1)))
#define AS3 __attribute__((address_space(3)))

__device__ __forceinline__ void gload_lds16(const void* g, void* l) {
  __builtin_amdgcn_global_load_lds((const AS1 void*)g, (AS3 void*)l, 16, 0, 0);
}

__device__ __forceinline__ unsigned short f2bf(float f) {
  unsigned int u = __float_as_uint(f);
  u += 0x7fffu + ((u >> 16) & 1u);
  return (unsigned short)(u >> 16);
}

// ---------------- x: fp32 -> bf16, 8 elems/thread ----------------
__global__ __launch_bounds__(256) void k_convert(const float* __restrict__ in,
                                                 unsigned short* __restrict__ out) {
  long i = (long)blockIdx.x * 256 + threadIdx.x;
  const float4* p = (const float4*)in + i * 2;
  float4 a = p[0], b = p[1];
  short8 o;
  o[0] = (short)f2bf(a.x); o[1] = (short)f2bf(a.y);
  o[2] = (short)f2bf(a.z); o[3] = (short)f2bf(a.w);
  o[4] = (short)f2bf(b.x); o[5] = (short)f2bf(b.y);
  o[6] = (short)f2bf(b.z); o[7] = (short)f2bf(b.w);
  ((short8*)out)[i] = o;
}

// ---------- W [K][N] fp32 -> WT [N][K] bf16 (64x64 tiles) ----------
__global__ __launch_bounds__(256) void k_transpose_w(const float* __restrict__ w,
                                                     unsigned short* __restrict__ wt,
                                                     int K, int N) {
  __shared__ float t[64][65];
  const int tilesN = N >> 6;
  const int tk = blockIdx.x / tilesN, tn = blockIdx.x % tilesN;
  const int c = threadIdx.x & 63, r0 = (threadIdx.x >> 6) * 16;
#pragma unroll
  for (int i = 0; i < 16; ++i)
    t[r0 + i][c] = w[(long)(tk * 64 + r0 + i) * N + tn * 64 + c];
  __syncthreads();
#pragma unroll
  for (int i = 0; i < 16; ++i)
    wt[(long)(tn * 64 + r0 + i) * K + tk * 64 + c] = f2bf(t[c][r0 + i]);
}

// ---------- V part of qkv -> VT [bh*64 + d][2048] bf16 ----------
__global__ __launch_bounds__(256) void k_transpose_v(const unsigned short* __restrict__ qkv,
                                                     unsigned short* __restrict__ vt) {
  __shared__ __align__(16) unsigned short t[64][72];
  const int tt = blockIdx.x & 31, bh = blockIdx.x >> 5;
  const int b = bh >> 4, h = bh & 15;
  const int r = threadIdx.x >> 2, c0 = (threadIdx.x & 3) * 16;
  const unsigned short* src = qkv + (long)(b * 2048 + tt * 64 + r) * 3072 + 2048 + h * 64 + c0;
  *(short8*)&t[r][c0] = *(const short8*)src;
  *(short8*)&t[r][c0 + 8] = *(const short8*)(src + 8);
  __syncthreads();
  short8 w0, w1;
#pragma unroll
  for (int i = 0; i < 8; ++i) w0[i] = (short)t[c0 + i][r];
#pragma unroll
  for (int i = 0; i < 8; ++i) w1[i] = (short)t[c0 + 8 + i][r];
  unsigned short* dst = vt + (long)(bh * 64 + r) * 2048 + tt * 64 + c0;
  *(short8*)dst = w0;
  *(short8*)(dst + 8) = w1;
}

// ---------- GEMM: C[M][N] = A[M][K] @ BT[N][K]^T + bias ----------
// 256x128 tile, 512 threads (8 waves 4Mx2N, 64x64 per wave), BK=64.
// Triple-buffered LDS (144KB), 2-deep prefetch with counted vmcnt(6),
// 4 phases per K-tile (ds_read || stage-issue -> 8 MFMA -> barrier),
// T2 XOR swizzle both-sides, T5 setprio, XCD-aware block swizzle.
template <int OUT_BF16>
__global__ __launch_bounds__(512) void k_gemm(const unsigned short* __restrict__ A,
                                              const unsigned short* __restrict__ BT,
                                              const float* __restrict__ bias,
                                              void* __restrict__ out,
                                              int M, int N, int K) {
  __shared__ __align__(16) unsigned short As[3][256 * 64];  // 96 KB
  __shared__ __align__(16) unsigned short Bs[3][128 * 64];  // 48 KB
  const int tid = threadIdx.x, lane = tid & 63, wid = tid >> 6;
  const int r16 = lane & 15, khi = lane >> 4;
  const int wm = wid >> 1, wn = wid & 1;
  const int tilesN = N >> 7;
  const int cpx = gridDim.x >> 3;  // grid % 8 == 0
  const int bid = ((int)blockIdx.x & 7) * cpx + ((int)blockIdx.x >> 3);
  const int tm = bid / tilesN, tn = bid % tilesN;
  const long m0 = (long)tm * 256, n0 = (long)tn * 128;
  f32x4 acc[4][4] = {};
  // staging: 8-row stripes per call; source col pre-swizzled by row&7 = lane>>3
  const int lr8 = lane >> 3;
  const int scol = ((lane & 7) ^ lr8) * 8;
  const unsigned short* aSrc = A + (m0 + wid * 32 + lr8) * K + scol;
  const unsigned short* bSrc = BT + (n0 + wid * 16 + lr8) * K + scol;
  const int nk = K >> 6;
  const int pc0 = (khi ^ (r16 & 7)) * 8;        // kk=0 swizzled chunk
  const int pc1 = ((4 + khi) ^ (r16 & 7)) * 8;  // kk=1 swizzled chunk

#define SA(buf, kt, c) gload_lds16(aSrc + (long)(kt) * 64 + (c) * 8 * K, &As[buf][wid * 2048 + (c) * 512])
#define SB(buf, kt, c) gload_lds16(bSrc + (long)(kt) * 64 + (c) * 8 * K, &Bs[buf][wid * 1024 + (c) * 512])
#define AF(m, pc) (*(const short8*)&Ab[(wm * 64 + (m) * 16 + r16) * 64 + (pc)])
#define BF(n, pc) (*(const short8*)&Bb[(wn * 64 + (n) * 16 + r16) * 64 + (pc)])

  // prologue: tiles 0 and 1 (12 loads in flight)
  SA(0, 0, 0); SA(0, 0, 1); SA(0, 0, 2); SA(0, 0, 3); SB(0, 0, 0); SB(0, 0, 1);
  if (nk > 1) { SA(1, 1, 0); SA(1, 1, 1); SA(1, 1, 2); SA(1, 1, 3); SB(1, 1, 0); SB(1, 1, 1); }

  int ct = 0;
  for (int t = 0; t < nk; ++t) {
    const int st = (ct + 2 >= 3) ? ct - 1 : ct + 2;  // buffer for tile t+2
    if (t + 1 < nk) asm volatile("s_waitcnt vmcnt(6)" ::: "memory");  // tile t landed
    else            asm volatile("s_waitcnt vmcnt(0)" ::: "memory");
    __builtin_amdgcn_s_barrier();
    const bool stg = (t + 2) < nk;
    const unsigned short* Ab = As[ct];
    const unsigned short* Bb = Bs[ct];
    short8 bf[4], af[2];

    // ---- phase 0: kk=0, m=0..1
    if (stg) { SA(st, t + 2, 0); SA(st, t + 2, 1); }
    bf[0] = BF(0, pc0); bf[1] = BF(1, pc0); bf[2] = BF(2, pc0); bf[3] = BF(3, pc0);
    af[0] = AF(0, pc0); af[1] = AF(1, pc0);
    __builtin_amdgcn_s_setprio(1);
#pragma unroll
    for (int n = 0; n < 4; ++n) {
      acc[0][n] = __builtin_amdgcn_mfma_f32_16x16x32_bf16(af[0], bf[n], acc[0][n], 0, 0, 0);
      acc[1][n] = __builtin_amdgcn_mfma_f32_16x16x32_bf16(af[1], bf[n], acc[1][n], 0, 0, 0);
    }
    __builtin_amdgcn_s_setprio(0);
    __builtin_amdgcn_s_barrier();

    // ---- phase 1: kk=0, m=2..3
    if (stg) { SA(st, t + 2, 2); SA(st, t + 2, 3); }
    af[0] = AF(2, pc0); af[1] = AF(3, pc0);
    __builtin_amdgcn_s_setprio(1);
#pragma unroll
    for (int n = 0; n < 4; ++n) {
      acc[2][n] = __builtin_amdgcn_mfma_f32_16x16x32_bf16(af[0], bf[n], acc[2][n], 0, 0, 0);
      acc[3][n] = __builtin_amdgcn_mfma_f32_16x16x32_bf16(af[1], bf[n], acc[3][n], 0, 0, 0);
    }
    __builtin_amdgcn_s_setprio(0);
    __builtin_amdgcn_s_barrier();

    // ---- phase 2: kk=1, m=0..1
    if (stg) { SB(st, t + 2, 0); SB(st, t + 2, 1); }
    bf[0] = BF(0, pc1); bf[1] = BF(1, pc1); bf[2] = BF(2, pc1); bf[3] = BF(3, pc1);
    af[0] = AF(0, pc1); af[1] = AF(1, pc1);
    __builtin_amdgcn_s_setprio(1);
#pragma unroll
    for (int n = 0; n < 4; ++n) {
      acc[0][n] = __builtin_amdgcn_mfma_f32_16x16x32_bf16(af[0], bf[n], acc[0][n], 0, 0, 0);
      acc[1][n] = __builtin_amdgcn_mfma_f32_16x16x32_bf16(af[1], bf[n], acc[1][n], 0, 0, 0);
    }
    __builtin_amdgcn_s_setprio(0);
    __builtin_amdgcn_s_barrier();

    // ---- phase 3: kk=1, m=2..3
    af[0] = AF(2, pc1); af[1] = AF(3, pc1);
    __builtin_amdgcn_s_setprio(1);
#pragma unroll
    for (int n = 0; n < 4; ++n) {
      acc[2][n] = __builtin_amdgcn_mfma_f32_16x16x32_bf16(af[0], bf[n], acc[2][n], 0, 0, 0);
      acc[3][n] = __builtin_amdgcn_mfma_f32_16x16x32_bf16(af[1], bf[n], acc[3][n], 0, 0, 0);
    }
    __builtin_amdgcn_s_setprio(0);
    __builtin_amdgcn_s_barrier();

    ct = (ct + 1 >= 3) ? 0 : ct + 1;
  }
#undef SA
#undef SB
#undef AF
#undef BF

  // epilogue: C layout col=lane&15, row=(lane>>4)*4+reg
#pragma unroll
  for (int m = 0; m < 4; ++m) {
    long row = m0 + wm * 64 + m * 16 + khi * 4;
#pragma unroll
    for (int n = 0; n < 4; ++n) {
      int col = (int)n0 + wn * 64 + n * 16 + r16;
      float bv = bias[col];
#pragma unroll
      for (int j = 0; j < 4; ++j) {
        float v = acc[m][n][j] + bv;
        if (OUT_BF16)
          ((unsigned short*)out)[(row + j) * N + col] = f2bf(v);
        else
          ((float*)out)[(row + j) * N + col] = v;
      }
    }
  }
}

// ---------- causal flash attention, QBLK=128, KVBLK=64, HDIM=64 ----------
// R9 version (validated): swapped MFMA, XOR-swizzled K/VT, dbuf + vmcnt(2),
// raw-domain max, fma+v_exp softmax, exact skip-rescale, v_perm P-pack.
__global__ __launch_bounds__(512) void k_attn(const unsigned short* __restrict__ qkv,
                                              const unsigned short* __restrict__ vt,
                                              unsigned short* __restrict__ aout) {
  __shared__ __align__(16) unsigned short Ks[2][64 * 64];
  __shared__ __align__(16) unsigned short VTs[2][64 * 64];
  __shared__ __align__(16) unsigned short Ps[8][16 * 72];
  const int tid = threadIdx.x, lane = tid & 63, wid = tid >> 6;
  const int r16 = lane & 15, khi = lane >> 4;
  const int qt = 15 - (int)(blockIdx.x >> 6), bh = blockIdx.x & 63;
  const int b = bh >> 4, h = bh & 15;
  const long qrow0 = (long)b * 2048 + qt * 128;

  const int srow = wid * 8 + (lane >> 3);
  const int lck = (lane & 7) ^ (srow & 7);
  const unsigned short* kbase =
      qkv + ((long)b * 2048 + srow) * 3072 + 1024 + h * 64 + lck * 8;
  const unsigned short* vbase = vt + ((long)bh * 64 + srow) * 2048 + lck * 8;

  const long qrow = qrow0 + wid * 16 + r16;
  const short8 qf0 = *(const short8*)&qkv[qrow * 3072 + h * 64 + khi * 8];
  const short8 qf1 = *(const short8*)&qkv[qrow * 3072 + h * 64 + 32 + khi * 8];

  gload_lds16(kbase, &Ks[0][wid * 512]);
  gload_lds16(vbase, &VTs[0][wid * 512]);

  const int ktmax = 2 * qt + 1;
  const int ktw = (qt * 128 + wid * 16 + 15) >> 6;
  const int qg = qt * 128 + wid * 16 + r16;
  const float SC = 0.18033688f;  // 0.125 * log2(e)
  float m_run = -1e30f, l_run = 0.f;
  f32x4 o[4] = {};

  for (int kt = 0; kt <= ktmax; ++kt) {
    const int cur = kt & 1;
    __builtin_amdgcn_s_barrier();
    if (kt < ktmax) {
      gload_lds16(kbase + (long)(kt + 1) * 64 * 3072, &Ks[cur ^ 1][wid * 512]);
      gload_lds16(vbase + (kt + 1) * 64, &VTs[cur ^ 1][wid * 512]);
      asm volatile("s_waitcnt vmcnt(2)" ::: "memory");
    } else {
      asm volatile("s_waitcnt vmcnt(0)" ::: "memory");
    }
    __builtin_amdgcn_s_barrier();
    if (kt > ktw) continue;

    f32x4 s[4] = {};
    __builtin_amdgcn_s_setprio(1);
#pragma unroll
    for (int kk = 0; kk < 2; ++kk) {
      const int pc = ((kk * 4 + khi) ^ (r16 & 7)) * 8;
      const short8 qf = kk ? qf1 : qf0;
#pragma unroll
      for (int n = 0; n < 4; ++n) {
        short8 kf = *(const short8*)&Ks[cur][(n * 16 + r16) * 64 + pc];
        s[n] = __builtin_amdgcn_mfma_f32_16x16x32_bf16(kf, qf, s[n], 0, 0, 0);
      }
    }
    __builtin_amdgcn_s_setprio(0);

    const bool need_mask = (kt * 64 + 63) > (qt * 128 + wid * 16);
    if (need_mask) {
      const int ktB = kt * 64;
#pragma unroll
      for (int n = 0; n < 4; ++n)
#pragma unroll
        for (int j = 0; j < 4; ++j)
          if ((ktB + n * 16 + khi * 4 + j) > qg) s[n][j] = -1e30f;
    }

    float pmn[4];
#pragma unroll
    for (int n = 0; n < 4; ++n)
      pmn[n] = fmaxf(fmaxf(s[n][0], s[n][1]), fmaxf(s[n][2], s[n][3]));
    float pm = fmaxf(fmaxf(pmn[0], pmn[1]), fmaxf(pmn[2], pmn[3]));
    pm = fmaxf(pm, __shfl_xor(pm, 16, 64));
    pm = fmaxf(pm, __shfl_xor(pm, 32, 64));
    const float pmS = pm * SC;
    const float mn = fmaxf(m_run, pmS);
    if (!__all(pmS <= m_run)) {
      const float alpha = __builtin_amdgcn_exp2f(m_run - mn);
      l_run *= alpha;
#pragma unroll
      for (int n = 0; n < 4; ++n)
#pragma unroll
        for (int j = 0; j < 4; ++j) o[n][j] *= alpha;
    }
    m_run = mn;

    const float nmn = -mn;
    float rsum = 0.f;
    unsigned int pk[8];
#pragma unroll
    for (int n = 0; n < 4; ++n) {
      float e0 = __builtin_amdgcn_exp2f(fmaf(s[n][0], SC, nmn));
      float e1 = __builtin_amdgcn_exp2f(fmaf(s[n][1], SC, nmn));
      float e2 = __builtin_amdgcn_exp2f(fmaf(s[n][2], SC, nmn));
      float e3 = __builtin_amdgcn_exp2f(fmaf(s[n][3], SC, nmn));
      rsum += (e0 + e1) + (e2 + e3);
      pk[n * 2] = __builtin_amdgcn_perm(__float_as_uint(e1), __float_as_uint(e0), 0x07060302u);
      pk[n * 2 + 1] = __builtin_amdgcn_perm(__float_as_uint(e3), __float_as_uint(e2), 0x07060302u);
    }
    rsum += __shfl_xor(rsum, 16, 64);
    rsum += __shfl_xor(rsum, 32, 64);
    l_run += rsum;

#pragma unroll
    for (int n = 0; n < 4; ++n) {
      uint2 pw = {pk[n * 2], pk[n * 2 + 1]};
      *(uint2*)&Ps[wid][r16 * 72 + n * 16 + khi * 4] = pw;
    }

    __builtin_amdgcn_s_setprio(1);
#pragma unroll
    for (int kk = 0; kk < 2; ++kk) {
      const short8 pf = *(const short8*)&Ps[wid][r16 * 72 + kk * 32 + khi * 8];
      const int pc = ((kk * 4 + khi) ^ (r16 & 7)) * 8;
#pragma unroll
      for (int n = 0; n < 4; ++n) {
        short8 vf = *(const short8*)&VTs[cur][(n * 16 + r16) * 64 + pc];
        o[n] = __builtin_amdgcn_mfma_f32_16x16x32_bf16(vf, pf, o[n], 0, 0, 0);
      }
    }
    __builtin_amdgcn_s_setprio(0);
  }

  const float inv = 1.f / l_run;
#pragma unroll
  for (int n = 0; n < 4; ++n) {
    s16x4 ow;
#pragma unroll
    for (int j = 0; j < 4; ++j) ow[j] = (short)f2bf(o[n][j] * inv);
    *(s16x4*)&aout[qrow * 1024 + h * 64 + n * 16 + khi * 4] = ow;
  }
}

extern "C" void kernel_launch(void* const* d_in, const int* in_sizes, int n_in,
                              void* d_out, int out_size, void* d_ws, size_t ws_size,
                              hipStream_t stream) {
  (void)in_sizes; (void)n_in; (void)out_size; (void)ws_size;
  const float* x = (const float*)d_in[0];
  const float* Wqkv = (const float*)d_in[1];
  const float* bqkv = (const float*)d_in[2];
  const float* Wout = (const float*)d_in[3];
  const float* bout = (const float*)d_in[4];
  char* ws = (char*)d_ws;
  // Buffer plan (peak 88 MB):
  //   xb    [8192][1024] bf16 @ 0        (16 MB)  -- dead after GEMM1; aout aliases it
  //   wqkvt [3072][1024] bf16 @ 16 MB    ( 6 MB)
  //   woutt [1024][1024] bf16 @ 22 MB    ( 2 MB)
  //   qkv   [8192][3072] bf16 @ 24 MB    (48 MB)
  //   vt    [4096][2048] bf16 @ 72 MB    (16 MB)
  unsigned short* xb    = (unsigned short*)(ws + 0);
  unsigned short* wqkvt = (unsigned short*)(ws + (16l << 20));
  unsigned short* woutt = (unsigned short*)(ws + (22l << 20));
  unsigned short* qkv   = (unsigned short*)(ws + (24l << 20));
  unsigned short* vt    = (unsigned short*)(ws + (72l << 20));
  unsigned short* aout  = xb;  // alias: xb dead after GEMM1

  k_convert<<<4096, 256, 0, stream>>>(x, xb);
  k_transpose_w<<<768, 256, 0, stream>>>(Wqkv, wqkvt, 1024, 3072);
  k_transpose_w<<<256, 256, 0, stream>>>(Wout, woutt, 1024, 1024);
  k_gemm<1><<<32 * 24, 512, 0, stream>>>(xb, wqkvt, bqkv, qkv, 8192, 3072, 1024);
  k_transpose_v<<<2048, 256, 0, stream>>>(qkv, vt);
  k_attn<<<16 * 64, 512, 0, stream>>>(qkv, vt, aout);
  k_gemm<0><<<32 * 8, 512, 0, stream>>>(aout, woutt, bout, d_out, 8192, 1024, 1024);
}